// Round 7
// baseline (283.505 us; speedup 1.0000x reference)
//
#include <hip/hip_runtime.h>
#include <cmath>

#define B_ 2
#define T_ 2048
#define D_ 1024
#define H_ 16
#define HD_ 64
#define M_ (B_ * T_)   // 4096
#define N3_ (3 * D_)   // 3072
#define K_ 1024

typedef _Float16 halfx8 __attribute__((ext_vector_type(8)));
typedef _Float16 halfx4 __attribute__((ext_vector_type(4)));
typedef float f32x4 __attribute__((ext_vector_type(4)));
typedef float f32x16 __attribute__((ext_vector_type(16)));

#define ASYNC_COPY16(gp, lp) \
  __builtin_amdgcn_global_load_lds((__attribute__((address_space(1))) void*)(gp), \
      (__attribute__((address_space(3))) void*)(lp), 16, 0, 0)

// q pre-scale: 1/sqrt(64) * log2(e)  (softmax in exp2 domain)
#define QSCALE 0.1803368801111204f

// slot base within a (b,h): q32<16:1 chunk, <32:2, <48:3, else 4 (160 total)
#define CBOF(q) ((q) < 16 ? (q) : (q) < 32 ? 16 + 2 * ((q) - 16) \
                 : (q) < 48 ? 48 + 3 * ((q) - 32) : 96 + 4 * ((q) - 48))
#define NSLOT 160
#define NITEM (32 * NSLOT)   // 5120

// ---------------------------------------------------------------------------
// fused fp32->fp16: x (2048 blocks), w_qkv (1536), w_out (512)
// ---------------------------------------------------------------------------
__global__ __launch_bounds__(256) void f2h_all(
    const float* __restrict__ x, const float* __restrict__ wq,
    const float* __restrict__ wo, _Float16* __restrict__ xh,
    _Float16* __restrict__ wqh, _Float16* __restrict__ woh)
{
    int bid = blockIdx.x;
    const float* s; _Float16* d; int off;
    if (bid < 2048)      { s = x;  d = xh;  off = bid; }
    else if (bid < 3584) { s = wq; d = wqh; off = bid - 2048; }
    else                 { s = wo; d = woh; off = bid - 3584; }
    int i = (off * 256 + threadIdx.x) * 8;
    float4 a = *(const float4*)(s + i);
    float4 b = *(const float4*)(s + i + 4);
    halfx8 h;
    h[0] = (_Float16)a.x; h[1] = (_Float16)a.y; h[2] = (_Float16)a.z; h[3] = (_Float16)a.w;
    h[4] = (_Float16)b.x; h[5] = (_Float16)b.y; h[6] = (_Float16)b.z; h[7] = (_Float16)b.w;
    *(halfx8*)(d + i) = h;
}

// mask -> additive bias + per-64-key-tile all-keep flag (wave = one tile)
__global__ __launch_bounds__(256) void maskprep(const float* __restrict__ mask,
                                                float* __restrict__ kbias,
                                                int* __restrict__ tflags)
{
    int i = blockIdx.x * 256 + threadIdx.x;
    float mv = mask[i];
    kbias[i] = (mv != 0.f) ? 0.f : -INFINITY;
    unsigned long long bal = __ballot(mv != 0.f);
    if ((threadIdx.x & 63) == 0) tflags[i >> 6] = (bal == ~0ULL) ? 1 : 0;
}

// ---------------------------------------------------------------------------
// GEMM1: qkv = x @ w_qkv^T + b_qkv (fp16 MFMA, 128x128 tile, BK=32).
// Scatter: q(scaled)->[b,h,t,hd]; k->[b,h,t,hd]; v->[b,h,hd,t]. Plain layouts
// (attention reads global->VGPR directly; no LDS swizzle needed).
// ---------------------------------------------------------------------------
__global__ __launch_bounds__(256) void gemm_qkv(
    const _Float16* __restrict__ A, const _Float16* __restrict__ Wt,
    const float* __restrict__ bias,
    _Float16* __restrict__ qh, _Float16* __restrict__ kh, _Float16* __restrict__ vth)
{
    __shared__ _Float16 As[128 * 32];
    __shared__ _Float16 Bs[128 * 32];
    const int tid = threadIdx.x;
    const int lane = tid & 63, w = tid >> 6;
    const int col = lane & 15, quad = lane >> 4;
    const int wr = w >> 1, wc = w & 1;
    const int m0 = blockIdx.y << 7, n0 = blockIdx.x << 7;

    const int c0 = w * 2, c1 = c0 + 1;
    const int r0 = c0 * 16 + (lane >> 2), r1 = c1 * 16 + (lane >> 2);
    const int ks = (lane & 3) << 3;

    f32x4 acc[4][4] = {};

    for (int k0 = 0; k0 < K_; k0 += 32) {
        ASYNC_COPY16(A  + (size_t)(m0 + r0) * K_ + k0 + ks, &As[c0 * 512]);
        ASYNC_COPY16(A  + (size_t)(m0 + r1) * K_ + k0 + ks, &As[c1 * 512]);
        ASYNC_COPY16(Wt + (size_t)(n0 + r0) * K_ + k0 + ks, &Bs[c0 * 512]);
        ASYNC_COPY16(Wt + (size_t)(n0 + r1) * K_ + k0 + ks, &Bs[c1 * 512]);
        __syncthreads();
        halfx8 af[4], bf[4];
#pragma unroll
        for (int i = 0; i < 4; ++i)
            af[i] = *(const halfx8*)&As[(wr * 64 + i * 16 + col) * 32 + quad * 8];
#pragma unroll
        for (int j = 0; j < 4; ++j)
            bf[j] = *(const halfx8*)&Bs[(wc * 64 + j * 16 + col) * 32 + quad * 8];
#pragma unroll
        for (int i = 0; i < 4; ++i)
#pragma unroll
            for (int j = 0; j < 4; ++j)
                acc[i][j] = __builtin_amdgcn_mfma_f32_16x16x32_f16(af[i], bf[j], acc[i][j], 0, 0, 0);
        __syncthreads();
    }

#pragma unroll
    for (int i = 0; i < 4; ++i) {
#pragma unroll
        for (int r = 0; r < 4; ++r) {
            int m = m0 + wr * 64 + i * 16 + quad * 4 + r;
            int bb = m >> 11, tt = m & (T_ - 1);
#pragma unroll
            for (int j = 0; j < 4; ++j) {
                int n = n0 + wc * 64 + j * 16 + col;
                float val = acc[i][j][r] + bias[n];
                int which = n >> 10, head = (n >> 6) & 15, dd = n & 63;
                if (which == 0)
                    qh[((size_t)(bb * H_ + head) * T_ + tt) * HD_ + dd] = (_Float16)(val * QSCALE);
                else if (which == 1)
                    kh[((size_t)(bb * H_ + head) * T_ + tt) * HD_ + dd] = (_Float16)val;
                else
                    vth[((size_t)(bb * H_ + head) * HD_ + dd) * T_ + tt] = (_Float16)val;
            }
        }
    }
}

// ---------------------------------------------------------------------------
// GEMM2: out = attn_out @ w_out^T + b_out (fp32 output)
// ---------------------------------------------------------------------------
__global__ __launch_bounds__(256) void gemm_out(
    const _Float16* __restrict__ A, const _Float16* __restrict__ Wt,
    const float* __restrict__ bias, float* __restrict__ C)
{
    __shared__ _Float16 As[128 * 32];
    __shared__ _Float16 Bs[128 * 32];
    const int tid = threadIdx.x;
    const int lane = tid & 63, w = tid >> 6;
    const int col = lane & 15, quad = lane >> 4;
    const int wr = w >> 1, wc = w & 1;
    const int m0 = blockIdx.y << 7, n0 = blockIdx.x << 7;

    const int c0 = w * 2, c1 = c0 + 1;
    const int r0 = c0 * 16 + (lane >> 2), r1 = c1 * 16 + (lane >> 2);
    const int ks = (lane & 3) << 3;

    f32x4 acc[4][4] = {};

    for (int k0 = 0; k0 < K_; k0 += 32) {
        ASYNC_COPY16(A  + (size_t)(m0 + r0) * K_ + k0 + ks, &As[c0 * 512]);
        ASYNC_COPY16(A  + (size_t)(m0 + r1) * K_ + k0 + ks, &As[c1 * 512]);
        ASYNC_COPY16(Wt + (size_t)(n0 + r0) * K_ + k0 + ks, &Bs[c0 * 512]);
        ASYNC_COPY16(Wt + (size_t)(n0 + r1) * K_ + k0 + ks, &Bs[c1 * 512]);
        __syncthreads();
        halfx8 af[4], bf[4];
#pragma unroll
        for (int i = 0; i < 4; ++i)
            af[i] = *(const halfx8*)&As[(wr * 64 + i * 16 + col) * 32 + quad * 8];
#pragma unroll
        for (int j = 0; j < 4; ++j)
            bf[j] = *(const halfx8*)&Bs[(wc * 64 + j * 16 + col) * 32 + quad * 8];
#pragma unroll
        for (int i = 0; i < 4; ++i)
#pragma unroll
            for (int j = 0; j < 4; ++j)
                acc[i][j] = __builtin_amdgcn_mfma_f32_16x16x32_f16(af[i], bf[j], acc[i][j], 0, 0, 0);
        __syncthreads();
    }

#pragma unroll
    for (int i = 0; i < 4; ++i) {
#pragma unroll
        for (int r = 0; r < 4; ++r) {
            int m = m0 + wr * 64 + i * 16 + quad * 4 + r;
#pragma unroll
            for (int j = 0; j < 4; ++j) {
                int n = n0 + wc * 64 + j * 16 + col;
                C[(size_t)m * D_ + n] = acc[i][j][r] + bias[n];
            }
        }
    }
}

// ---------------------------------------------------------------------------
// Flash attention v7: BARRIER-FREE, LDS-FREE. One wave = one work item
// (bh, 32-q-strip, 512-key chunk). K/V fragments load global->VGPR directly
// in MFMA A-operand layout (transposed-S makes them row-contiguous). K is
// register-double-buffered one tile ahead; V issued at iter start, consumed
// ~400cy later. 5120 uniform items in 1280 blocks x 4 independent waves.
// blockIdx->bh swizzle keeps each XCD's K/V working set ~2MB (L2-resident).
// ---------------------------------------------------------------------------
__device__ __forceinline__ void load_k(halfx8 kf[8], const _Float16* kp,
                                       int kt, int l31, int q2)
{
#pragma unroll
    for (int kb2 = 0; kb2 < 2; ++kb2)
#pragma unroll
        for (int hc = 0; hc < 4; ++hc)
            kf[kb2 * 4 + hc] = *(const halfx8*)(kp +
                (size_t)(kt * 64 + kb2 * 32 + l31) * HD_ + hc * 16 + q2 * 8);
}

__device__ __forceinline__ void load_v(halfx4 vf[16], const _Float16* vp,
                                       int kt, int l31, int q2)
{
#pragma unroll
    for (int db = 0; db < 2; ++db)
#pragma unroll
        for (int ck = 0; ck < 8; ++ck)
            vf[db * 8 + ck] = *(const halfx4*)(vp +
                (size_t)(db * 32 + l31) * T_ + kt * 64 + ck * 8 + q2 * 4);
}

__device__ __forceinline__ void tile_compute(
    const halfx8 kf[8], const halfx4 vf[16], const halfx8 bq[4],
    int kt, int q32, int q_row, int l31, int q2,
    const float* kb, const int* tf,
    float& mrow, float& lrow, f32x16 oacc[2])
{
    // S^T = K·Q^T
    f32x16 sa[2];
#pragma unroll
    for (int kb2 = 0; kb2 < 2; ++kb2) {
        f32x16 a;
#pragma unroll
        for (int r = 0; r < 16; ++r) a[r] = 0.f;
#pragma unroll
        for (int hc = 0; hc < 4; ++hc)
            a = __builtin_amdgcn_mfma_f32_32x32x16_f16(kf[kb2 * 4 + hc], bq[hc], a, 0, 0, 0);
        sa[kb2] = a;
    }

    // running max on raw scores (valid upper bound; bias only 0/-inf)
    float mx = sa[0][0];
#pragma unroll
    for (int r = 1; r < 16; ++r) mx = fmaxf(mx, sa[0][r]);
#pragma unroll
    for (int r = 0; r < 16; ++r) mx = fmaxf(mx, sa[1][r]);
    mx = fmaxf(mx, __shfl_xor(mx, 32, 64));
    float mold = mrow;
    float mnew = fmaxf(mold, mx);
    unsigned long long bump = __ballot(mnew > mold);
    mrow = mnew;

    // P = exp2(s [+bias] - m), packed straight into 32x32x8 B-frags
    const bool interior = (kt * 64 + 63 <= q32 * 32);  // wave-uniform
    const int allkeep = tf[kt];
    halfx4 pf[2][4];
    float rsum = 0.f;
    if (interior && allkeep) {
#pragma unroll
        for (int kb2 = 0; kb2 < 2; ++kb2)
#pragma unroll
            for (int cc = 0; cc < 4; ++cc)
#pragma unroll
                for (int j = 0; j < 4; ++j) {
                    float pv = exp2f(sa[kb2][cc * 4 + j] - mnew);
                    rsum += pv;
                    pf[kb2][cc][j] = (_Float16)pv;
                }
    } else {
#pragma unroll
        for (int kb2 = 0; kb2 < 2; ++kb2)
#pragma unroll
            for (int cc = 0; cc < 4; ++cc)
#pragma unroll
                for (int j = 0; j < 4; ++j) {
                    int key = kt * 64 + kb2 * 32 + j + 8 * cc + 4 * q2;
                    float add = 0.f;
                    if (!allkeep) add = kb[key];
                    float pv = (key <= q_row) ? exp2f(sa[kb2][cc * 4 + j] + add - mnew) : 0.f;
                    rsum += pv;
                    pf[kb2][cc][j] = (_Float16)pv;
                }
    }
    rsum += __shfl_xor(rsum, 32, 64);

    if (bump) {
        float alpha = exp2f(mold - mnew);
        lrow = lrow * alpha + rsum;
#pragma unroll
        for (int db = 0; db < 2; ++db)
#pragma unroll
            for (int r = 0; r < 16; ++r) oacc[db][r] *= alpha;
    } else {
        lrow += rsum;
    }

    // O^T += V^T·P^T
#pragma unroll
    for (int db = 0; db < 2; ++db)
#pragma unroll
        for (int kb2 = 0; kb2 < 2; ++kb2)
#pragma unroll
            for (int cc = 0; cc < 4; ++cc)
                oacc[db] = __builtin_amdgcn_mfma_f32_32x32x8f16(
                    vf[db * 8 + kb2 * 4 + cc], pf[kb2][cc], oacc[db], 0, 0, 0);
}

__global__ __launch_bounds__(256, 2) void attn_kernel(
    const _Float16* __restrict__ qh, const _Float16* __restrict__ kh,
    const _Float16* __restrict__ vth, const float* __restrict__ kbias,
    const int* __restrict__ tflags,
    float* __restrict__ pm, float* __restrict__ pl, _Float16* __restrict__ po)
{
    const int bid = blockIdx.x;
    const int xcd = bid & 7, g = (bid >> 3) & 3, s4 = bid >> 5;  // s4 in [0,40)
    const int bh = xcd * 4 + g;
    const int b = bh >> 4, h = bh & 15;
    const int lane = threadIdx.x & 63, w = threadIdx.x >> 6;
    const int l31 = lane & 31, q2 = lane >> 5;
    const int s = s4 * 4 + w;   // item slot [0,160)

    // decode slot -> (q32, chunk)
    int q32, c;
    if (s < 16)      { q32 = s;                c = 0; }
    else if (s < 48) { q32 = 16 + ((s - 16) >> 1); c = (s - 16) & 1; }
    else if (s < 96) { q32 = 32 + (s - 48) / 3;    c = (s - 48) % 3; }
    else             { q32 = 48 + ((s - 96) >> 2); c = (s - 96) & 3; }

    const int qmax = q32 * 32 + 31;
    const int kt0 = c * 8;
    const int ktend = min(kt0 + 7, qmax >> 6);

    const size_t hbo = (size_t)bh;
    const _Float16* qp = qh + hbo * T_ * HD_;
    const _Float16* kp = kh + hbo * T_ * HD_;
    const _Float16* vp = vth + hbo * HD_ * T_;
    const float* kb = kbias + (size_t)b * T_;
    const int* tf = tflags + b * 32;

    const int q_row = q32 * 32 + l31;

    // Q B-frags: B[n=q=l31][k = hc*16 + q2*8 + j]
    halfx8 bq[4];
#pragma unroll
    for (int hc = 0; hc < 4; ++hc)
        bq[hc] = *(const halfx8*)(qp + (size_t)q_row * HD_ + hc * 16 + q2 * 8);

    float mrow = -INFINITY, lrow = 0.f;
    f32x16 oacc[2] = {};

    halfx8 kf0[8], kf1[8];
    halfx4 vf[16];

    load_k(kf0, kp, kt0, l31, q2);

    for (int kt = kt0; kt <= ktend; kt += 2) {
        load_v(vf, vp, kt, l31, q2);
        if (kt + 1 <= ktend) load_k(kf1, kp, kt + 1, l31, q2);
        tile_compute(kf0, vf, bq, kt, q32, q_row, l31, q2, kb, tf, mrow, lrow, oacc);
        if (kt + 1 <= ktend) {
            load_v(vf, vp, kt + 1, l31, q2);
            if (kt + 2 <= ktend) load_k(kf0, kp, kt + 2, l31, q2);
            tile_compute(kf1, vf, bq, kt + 1, q32, q_row, l31, q2, kb, tf, mrow, lrow, oacc);
        }
    }

    // epilogue: write partials (m, l fp32; O^T fp16 unnormalized)
    const int slot = bh * NSLOT + CBOF(q32) + c;
    if (q2 == 0) {
        pm[(size_t)slot * 32 + l31] = mrow;
        pl[(size_t)slot * 32 + l31] = lrow;
    }
    _Float16* pob = po + ((size_t)slot * 32 + l31) * 64;
#pragma unroll
    for (int db = 0; db < 2; ++db)
#pragma unroll
        for (int gg = 0; gg < 4; ++gg) {
            halfx4 ov;
#pragma unroll
            for (int j = 0; j < 4; ++j)
                ov[j] = (_Float16)(oacc[db][gg * 4 + j]);
            *(halfx4*)(pob + db * 32 + 8 * gg + 4 * q2) = ov;
        }
}

// ---------------------------------------------------------------------------
// Combine partials: block per (256 q-rows, h, b); thread = one q-row.
// ---------------------------------------------------------------------------
__global__ __launch_bounds__(256) void attn_combine(
    const float* __restrict__ pm, const float* __restrict__ pl,
    const _Float16* __restrict__ po, _Float16* __restrict__ oh)
{
    const int h = blockIdx.y, b = blockIdx.z;
    const int r = blockIdx.x * 256 + threadIdx.x;   // q-row within (b,h)
    const int q32 = r >> 5, rl = r & 31;
    const int nc = (q32 >> 4) + 1;
    const int slot0 = (b * H_ + h) * NSLOT + CBOF(q32);

    float mc[4], lc[4];
    float mstar = -INFINITY;
    for (int cc = 0; cc < nc; ++cc) {
        mc[cc] = pm[(size_t)(slot0 + cc) * 32 + rl];
        lc[cc] = pl[(size_t)(slot0 + cc) * 32 + rl];
        mstar = fmaxf(mstar, mc[cc]);
    }
    float lstar = 0.f, wc[4];
    for (int cc = 0; cc < nc; ++cc) {
        wc[cc] = exp2f(mc[cc] - mstar);
        lstar += wc[cc] * lc[cc];
    }
    float acc[64] = {};
    for (int cc = 0; cc < nc; ++cc) {
        const _Float16* src = po + ((size_t)(slot0 + cc) * 32 + rl) * 64;
        float wv = wc[cc];
#pragma unroll
        for (int gg = 0; gg < 8; ++gg) {
            halfx8 hv = *(const halfx8*)(src + gg * 8);
#pragma unroll
            for (int j = 0; j < 8; ++j)
                acc[gg * 8 + j] += wv * (float)hv[j];
        }
    }
    float linv = 1.f / lstar;
    _Float16* dst = oh + ((size_t)(b * T_ + r)) * D_ + h * 64;
#pragma unroll
    for (int gg = 0; gg < 8; ++gg) {
        halfx8 ov;
#pragma unroll
        for (int j = 0; j < 8; ++j)
            ov[j] = (_Float16)(acc[gg * 8 + j] * linv);
        *(halfx8*)(dst + gg * 8) = ov;
    }
}

// ---------------------------------------------------------------------------
extern "C" void kernel_launch(void* const* d_in, const int* in_sizes, int n_in,
                              void* d_out, int out_size, void* d_ws, size_t ws_size,
                              hipStream_t stream)
{
    (void)in_sizes; (void)n_in; (void)out_size; (void)ws_size;
    const float* x     = (const float*)d_in[0];
    const float* mask  = (const float*)d_in[1];
    const float* w_qkv = (const float*)d_in[2];
    const float* b_qkv = (const float*)d_in[3];
    const float* w_out = (const float*)d_in[4];
    const float* b_out = (const float*)d_in[5];
    float* out = (float*)d_out;

    const size_t QKV1 = (size_t)B_ * H_ * T_ * HD_;   // 4M halfs
    _Float16* xh  = (_Float16*)d_ws;
    _Float16* wqh = xh  + (size_t)M_ * K_;
    _Float16* woh = wqh + (size_t)N3_ * K_;
    _Float16* qh  = woh + (size_t)D_ * K_;
    _Float16* kh  = qh  + QKV1;
    _Float16* vth = kh  + QKV1;
    _Float16* oh  = vth + QKV1;
    _Float16* po  = oh  + QKV1;                        // NITEM*32*64 halfs
    float* kbias  = (float*)(po + (size_t)NITEM * 32 * 64);
    float* pm     = kbias + (size_t)B_ * T_;           // NITEM*32 floats
    float* pl     = pm + (size_t)NITEM * 32;
    int* tflags   = (int*)(pl + (size_t)NITEM * 32);   // 64 ints

    f2h_all<<<4096, 256, 0, stream>>>(x, w_qkv, w_out, xh, wqh, woh);
    maskprep<<<(B_ * T_) / 256, 256, 0, stream>>>(mask, kbias, tflags);

    gemm_qkv<<<dim3(N3_ / 128, M_ / 128), 256, 0, stream>>>(
        xh, wqh, b_qkv, qh, kh, vth);
    attn_kernel<<<dim3(NITEM / 4, 1, 1), 256, 0, stream>>>(
        qh, kh, vth, kbias, tflags, pm, pl, po);
    attn_combine<<<dim3(T_ / 256, H_, B_), 256, 0, stream>>>(
        pm, pl, po, oh);
    gemm_out<<<dim3(D_ / 128, M_ / 128), 256, 0, stream>>>(
        oh, woh, b_out, out);
}

// Round 8
// 210.863 us; speedup vs baseline: 1.3445x; 1.3445x over previous
//
#include <hip/hip_runtime.h>
#include <cmath>

#define B_ 2
#define T_ 2048
#define D_ 1024
#define H_ 16
#define HD_ 64
#define M_ (B_ * T_)   // 4096
#define N3_ (3 * D_)   // 3072
#define K_ 1024

typedef _Float16 halfx8 __attribute__((ext_vector_type(8)));
typedef _Float16 halfx4 __attribute__((ext_vector_type(4)));
typedef float f32x4 __attribute__((ext_vector_type(4)));
typedef float f32x16 __attribute__((ext_vector_type(16)));

#define ASYNC_COPY16(gp, lp) \
  __builtin_amdgcn_global_load_lds((__attribute__((address_space(1))) void*)(gp), \
      (__attribute__((address_space(3))) void*)(lp), 16, 0, 0)

// q pre-scale: 1/sqrt(64) * log2(e)  (softmax in exp2 domain)
#define QSCALE 0.1803368801111204f

// chunk = 4 key-tiles (256 keys). nc(qt) = ceil((qt+1)/2), 72 items per (b,h).
__device__ const int QT_OF[72] = {
    15,15,15,15,15,15,15,15, 14,14,14,14,14,14,14,14,
    13,13,13,13,13,13,13, 12,12,12,12,12,12,12,
    11,11,11,11,11,11, 10,10,10,10,10,10,
    9,9,9,9,9, 8,8,8,8,8, 7,7,7,7, 6,6,6,6,
    5,5,5, 4,4,4, 3,3, 2,2, 1, 0};
__device__ const int C_OF[72] = {
    0,1,2,3,4,5,6,7, 0,1,2,3,4,5,6,7,
    0,1,2,3,4,5,6, 0,1,2,3,4,5,6,
    0,1,2,3,4,5, 0,1,2,3,4,5,
    0,1,2,3,4, 0,1,2,3,4, 0,1,2,3, 0,1,2,3,
    0,1,2, 0,1,2, 0,1, 0,1, 0, 0};
__device__ const int CB_OF[16] = {0,1,2,4,6,9,12,16,20,25,30,36,42,49,56,64};
__device__ const int NC_OF[16] = {1,1,2,2,3,3,4,4,5,5,6,6,7,7,8,8};
#define NSLOT 72        // pm/pl slots per (b,h)
#define NPOSLOT 56      // po slots per (b,h) (c>0 only; c=0 lives in oh)

// ---------------------------------------------------------------------------
// fused prep: fp32->fp16 for x (2048 blks), w_qkv (1536), w_out (512);
// mask -> additive bias + per-64-key-tile all-keep flags (16 blks).
// ---------------------------------------------------------------------------
__global__ __launch_bounds__(256) void prep_all(
    const float* __restrict__ x, const float* __restrict__ wq,
    const float* __restrict__ wo, const float* __restrict__ mask,
    _Float16* __restrict__ xh, _Float16* __restrict__ wqh,
    _Float16* __restrict__ woh, float* __restrict__ kbias,
    int* __restrict__ tflags)
{
    int bid = blockIdx.x;
    if (bid >= 4096) {   // mask prep
        int i = (bid - 4096) * 256 + threadIdx.x;
        float mv = mask[i];
        kbias[i] = (mv != 0.f) ? 0.f : -INFINITY;
        unsigned long long bal = __ballot(mv != 0.f);
        if ((threadIdx.x & 63) == 0) tflags[i >> 6] = (bal == ~0ULL) ? 1 : 0;
        return;
    }
    const float* s; _Float16* d; int off;
    if (bid < 2048)      { s = x;  d = xh;  off = bid; }
    else if (bid < 3584) { s = wq; d = wqh; off = bid - 2048; }
    else                 { s = wo; d = woh; off = bid - 3584; }
    int i = (off * 256 + threadIdx.x) * 8;
    float4 a = *(const float4*)(s + i);
    float4 b = *(const float4*)(s + i + 4);
    halfx8 h;
    h[0] = (_Float16)a.x; h[1] = (_Float16)a.y; h[2] = (_Float16)a.z; h[3] = (_Float16)a.w;
    h[4] = (_Float16)b.x; h[5] = (_Float16)b.y; h[6] = (_Float16)b.z; h[7] = (_Float16)b.w;
    *(halfx8*)(d + i) = h;
}

// ---------------------------------------------------------------------------
// GEMM1: qkv = x @ w_qkv^T + b_qkv (fp16 MFMA, 128x128 tile, BK=32).
// Scatter: q(scaled)->[b,h,t,hd]; k->[b,h,t,hd], v->[b,h,hd,t], both with
// full-rank 16B-seg XOR swizzle (^row&7 ^ (row>>3)&7) so attn's LDS
// ds_read_b128/b64 are conflict-free for lanes 1..31 apart. [verified R6]
// ---------------------------------------------------------------------------
__global__ __launch_bounds__(256) void gemm_qkv(
    const _Float16* __restrict__ A, const _Float16* __restrict__ Wt,
    const float* __restrict__ bias,
    _Float16* __restrict__ qh, _Float16* __restrict__ kh, _Float16* __restrict__ vth)
{
    __shared__ _Float16 As[128 * 32];
    __shared__ _Float16 Bs[128 * 32];
    const int tid = threadIdx.x;
    const int lane = tid & 63, w = tid >> 6;
    const int col = lane & 15, quad = lane >> 4;
    const int wr = w >> 1, wc = w & 1;
    const int m0 = blockIdx.y << 7, n0 = blockIdx.x << 7;

    const int c0 = w * 2, c1 = c0 + 1;
    const int r0 = c0 * 16 + (lane >> 2), r1 = c1 * 16 + (lane >> 2);
    const int ks = (lane & 3) << 3;

    f32x4 acc[4][4] = {};

    for (int k0 = 0; k0 < K_; k0 += 32) {
        ASYNC_COPY16(A  + (size_t)(m0 + r0) * K_ + k0 + ks, &As[c0 * 512]);
        ASYNC_COPY16(A  + (size_t)(m0 + r1) * K_ + k0 + ks, &As[c1 * 512]);
        ASYNC_COPY16(Wt + (size_t)(n0 + r0) * K_ + k0 + ks, &Bs[c0 * 512]);
        ASYNC_COPY16(Wt + (size_t)(n0 + r1) * K_ + k0 + ks, &Bs[c1 * 512]);
        __syncthreads();
        halfx8 af[4], bf[4];
#pragma unroll
        for (int i = 0; i < 4; ++i)
            af[i] = *(const halfx8*)&As[(wr * 64 + i * 16 + col) * 32 + quad * 8];
#pragma unroll
        for (int j = 0; j < 4; ++j)
            bf[j] = *(const halfx8*)&Bs[(wc * 64 + j * 16 + col) * 32 + quad * 8];
#pragma unroll
        for (int i = 0; i < 4; ++i)
#pragma unroll
            for (int j = 0; j < 4; ++j)
                acc[i][j] = __builtin_amdgcn_mfma_f32_16x16x32_f16(af[i], bf[j], acc[i][j], 0, 0, 0);
        __syncthreads();
    }

#pragma unroll
    for (int i = 0; i < 4; ++i) {
#pragma unroll
        for (int r = 0; r < 4; ++r) {
            int m = m0 + wr * 64 + i * 16 + quad * 4 + r;
            int bb = m >> 11, tt = m & (T_ - 1);
#pragma unroll
            for (int j = 0; j < 4; ++j) {
                int n = n0 + wc * 64 + j * 16 + col;
                float val = acc[i][j][r] + bias[n];
                int which = n >> 10, head = (n >> 6) & 15, dd = n & 63;
                if (which == 0) {
                    qh[((size_t)(bb * H_ + head) * T_ + tt) * HD_ + dd] = (_Float16)(val * QSCALE);
                } else if (which == 1) {
                    int hi = ((dd >> 3) ^ (tt & 7) ^ ((tt >> 3) & 7)) & 7;
                    int dds = (hi << 3) | (dd & 7);
                    kh[((size_t)(bb * H_ + head) * T_ + tt) * HD_ + dds] = (_Float16)val;
                } else {
                    int hi = (((tt >> 3) & 7) ^ (dd & 7) ^ ((dd >> 3) & 7)) & 7;
                    int tts = (tt & ~63) | (hi << 3) | (tt & 7);
                    vth[((size_t)(bb * H_ + head) * HD_ + dd) * T_ + tts] = (_Float16)val;
                }
            }
        }
    }
}

// ---------------------------------------------------------------------------
// GEMM2: out = attn_out @ w_out^T + b_out (fp32 out). 128x64 tile -> 512
// blocks = 2/CU (was 1/CU at 128x128: fully-exposed barrier drains).
// ---------------------------------------------------------------------------
__global__ __launch_bounds__(256) void gemm_out(
    const _Float16* __restrict__ A, const _Float16* __restrict__ Wt,
    const float* __restrict__ bias, float* __restrict__ C)
{
    __shared__ _Float16 As[128 * 32];
    __shared__ _Float16 Bs[64 * 32];
    const int tid = threadIdx.x;
    const int lane = tid & 63, w = tid >> 6;
    const int col = lane & 15, quad = lane >> 4;
    const int m0 = blockIdx.y << 7, n0 = blockIdx.x << 6;

    const int c0 = w * 2, c1 = c0 + 1;
    const int rA0 = c0 * 16 + (lane >> 2), rA1 = c1 * 16 + (lane >> 2);
    const int rB = w * 16 + (lane >> 2);
    const int ks = (lane & 3) << 3;

    f32x4 acc[2][4] = {};

    for (int k0 = 0; k0 < K_; k0 += 32) {
        ASYNC_COPY16(A  + (size_t)(m0 + rA0) * K_ + k0 + ks, &As[c0 * 512]);
        ASYNC_COPY16(A  + (size_t)(m0 + rA1) * K_ + k0 + ks, &As[c1 * 512]);
        ASYNC_COPY16(Wt + (size_t)(n0 + rB) * K_ + k0 + ks, &Bs[w * 512]);
        __syncthreads();
        halfx8 af[2], bf[4];
#pragma unroll
        for (int i = 0; i < 2; ++i)
            af[i] = *(const halfx8*)&As[(w * 32 + i * 16 + col) * 32 + quad * 8];
#pragma unroll
        for (int j = 0; j < 4; ++j)
            bf[j] = *(const halfx8*)&Bs[(j * 16 + col) * 32 + quad * 8];
#pragma unroll
        for (int i = 0; i < 2; ++i)
#pragma unroll
            for (int j = 0; j < 4; ++j)
                acc[i][j] = __builtin_amdgcn_mfma_f32_16x16x32_f16(af[i], bf[j], acc[i][j], 0, 0, 0);
        __syncthreads();
    }

#pragma unroll
    for (int i = 0; i < 2; ++i) {
#pragma unroll
        for (int r = 0; r < 4; ++r) {
            int m = m0 + w * 32 + i * 16 + quad * 4 + r;
#pragma unroll
            for (int j = 0; j < 4; ++j) {
                int n = n0 + j * 16 + col;
                C[(size_t)m * D_ + n] = acc[i][j][r] + bias[n];
            }
        }
    }
}

// ---------------------------------------------------------------------------
// Flash attention v8 = v5 structure (best measured) + full-rank swizzle +
// 256-key chunks. Block = (qt, c): 128 q-rows x 4 key-tiles, 4 waves x 32 q.
// K/V double-buffered global_load_lds; transposed-S; register-packed P.
// 2304 blocks. c==0 partials go straight to oh; c>0 to po.
// ---------------------------------------------------------------------------
__global__ __launch_bounds__(256) void attn_kernel(
    const _Float16* __restrict__ qh, const _Float16* __restrict__ kh,
    const _Float16* __restrict__ vth, const float* __restrict__ kbias,
    const int* __restrict__ tflags,
    float* __restrict__ pm, float* __restrict__ pl,
    _Float16* __restrict__ po, _Float16* __restrict__ oh)
{
    __shared__ _Float16 Ks[2][64 * 64];
    __shared__ _Float16 Vt[2][64 * 64];

    const int xi = blockIdx.x;
    const int qt = QT_OF[xi], c = C_OF[xi];
    const int h = blockIdx.y, b = blockIdx.z;
    const int tid = threadIdx.x;
    const int lane = tid & 63, w = tid >> 6;
    const int l31 = lane & 31, q2 = lane >> 5;

    const int kt0 = c * 4;
    const int ktend = min(2 * qt + 1, kt0 + 3);

    const int bh = b * H_ + h;
    const _Float16* qp = qh + (size_t)bh * T_ * HD_;
    const _Float16* kp = kh + (size_t)bh * T_ * HD_;
    const _Float16* vp = vth + (size_t)bh * HD_ * T_;
    const float* kb = kbias + (size_t)b * T_;
    const int* tf = tflags + b * 32;

    const int qbase = qt * 128 + w * 32;
    const int q_row = qbase + l31;

    // Q B-frags: B[n=q=l31][k = hc*16 + q2*8 + j]
    halfx8 bq[4];
#pragma unroll
    for (int hc = 0; hc < 4; ++hc)
        bq[hc] = *(const halfx8*)(qp + (size_t)q_row * HD_ + hc * 16 + q2 * 8);

    float mrow = -INFINITY, lrow = 0.f;
    f32x16 oacc[2] = {};

    // prologue: stage tile kt0 into buffer 0
    {
        const _Float16* ksrc = kp + (size_t)(kt0 * 64 + w * 16) * HD_;
        ASYNC_COPY16(ksrc + lane * 8, &Ks[0][(w * 16) * 64]);
        ASYNC_COPY16(ksrc + 8 * HD_ + lane * 8, &Ks[0][(w * 16 + 8) * 64]);
        const _Float16* vsrc = vp + (size_t)(w * 16 + (lane >> 3)) * T_
                                 + kt0 * 64 + (lane & 7) * 8;
        ASYNC_COPY16(vsrc, &Vt[0][(w * 16) * 64]);
        ASYNC_COPY16(vsrc + 8 * T_, &Vt[0][(w * 16 + 8) * 64]);
    }

    for (int kt = kt0; kt <= ktend; ++kt) {
        const int cur = (kt - kt0) & 1;
        __syncthreads();   // drains async copies for tile kt
        if (kt < ktend) {  // prefetch next tile into other buffer
            const int nb = cur ^ 1;
            const _Float16* ksrc = kp + (size_t)((kt + 1) * 64 + w * 16) * HD_;
            ASYNC_COPY16(ksrc + lane * 8, &Ks[nb][(w * 16) * 64]);
            ASYNC_COPY16(ksrc + 8 * HD_ + lane * 8, &Ks[nb][(w * 16 + 8) * 64]);
            const _Float16* vsrc = vp + (size_t)(w * 16 + (lane >> 3)) * T_
                                     + (kt + 1) * 64 + (lane & 7) * 8;
            ASYNC_COPY16(vsrc, &Vt[nb][(w * 16) * 64]);
            ASYNC_COPY16(vsrc + 8 * T_, &Vt[nb][(w * 16 + 8) * 64]);
        }
        if (kt * 64 > qbase + 31) continue;   // wave-uniform skip

        // S^T = K·Q^T : A = K rows (swizzled LDS), B = Q regs
        f32x16 sa[2];
#pragma unroll
        for (int kb2 = 0; kb2 < 2; ++kb2) {
            f32x16 a;
#pragma unroll
            for (int r = 0; r < 16; ++r) a[r] = 0.f;
#pragma unroll
            for (int hc = 0; hc < 4; ++hc) {
                int seg = (hc * 2 + q2) ^ (l31 & 7) ^ ((kb2 * 4 + (l31 >> 3)) & 7);
                halfx8 ka = *(const halfx8*)&Ks[cur][(kb2 * 32 + l31) * 64 + seg * 8];
                a = __builtin_amdgcn_mfma_f32_32x32x16_f16(ka, bq[hc], a, 0, 0, 0);
            }
            sa[kb2] = a;
        }

        // running max on raw scores (upper bound; bias only 0/-inf)
        float mx = sa[0][0];
#pragma unroll
        for (int r = 1; r < 16; ++r) mx = fmaxf(mx, sa[0][r]);
#pragma unroll
        for (int r = 0; r < 16; ++r) mx = fmaxf(mx, sa[1][r]);
        mx = fmaxf(mx, __shfl_xor(mx, 32, 64));
        float mold = mrow;
        float mnew = fmaxf(mold, mx);
        unsigned long long bump = __ballot(mnew > mold);
        mrow = mnew;

        // P = exp2(s [+bias] - m), packed into 32x32x8 B-frags
        const bool interior = (kt * 64 + 63 <= qbase);   // wave-uniform
        const int allkeep = tf[kt];
        halfx4 pf[2][4];
        float rsum = 0.f;
        if (interior && allkeep) {
#pragma unroll
            for (int kb2 = 0; kb2 < 2; ++kb2)
#pragma unroll
                for (int cc = 0; cc < 4; ++cc)
#pragma unroll
                    for (int j = 0; j < 4; ++j) {
                        float pv = exp2f(sa[kb2][cc * 4 + j] - mnew);
                        rsum += pv;
                        pf[kb2][cc][j] = (_Float16)pv;
                    }
        } else {
#pragma unroll
            for (int kb2 = 0; kb2 < 2; ++kb2)
#pragma unroll
                for (int cc = 0; cc < 4; ++cc)
#pragma unroll
                    for (int j = 0; j < 4; ++j) {
                        int key = kt * 64 + kb2 * 32 + j + 8 * cc + 4 * q2;
                        float add = allkeep ? 0.f : kb[key];
                        float pv = (key <= q_row) ? exp2f(sa[kb2][cc * 4 + j] + add - mnew) : 0.f;
                        rsum += pv;
                        pf[kb2][cc][j] = (_Float16)pv;
                    }
        }
        rsum += __shfl_xor(rsum, 32, 64);

        if (bump) {
            float alpha = exp2f(mold - mnew);
            lrow = lrow * alpha + rsum;
#pragma unroll
            for (int db = 0; db < 2; ++db)
#pragma unroll
                for (int r = 0; r < 16; ++r) oacc[db][r] *= alpha;
        } else {
            lrow += rsum;
        }

        // O^T += V^T·P^T : A = V^T rows (swizzled LDS), B = pf regs
#pragma unroll
        for (int db = 0; db < 2; ++db)
#pragma unroll
            for (int kb2 = 0; kb2 < 2; ++kb2)
#pragma unroll
                for (int cc = 0; cc < 4; ++cc) {
                    int ck = kb2 * 4 + cc;
                    int seg = ck ^ (l31 & 7) ^ ((db * 4 + (l31 >> 3)) & 7);
                    halfx4 va = *(const halfx4*)&Vt[cur][(db * 32 + l31) * 64 + seg * 8 + q2 * 4];
                    oacc[db] = __builtin_amdgcn_mfma_f32_32x32x8f16(va, pf[kb2][cc], oacc[db], 0, 0, 0);
                }
    }

    // epilogue: partials. m,l always to pm/pl; O^T to oh (c==0) or po (c>0).
    const int qloc = w * 32 + l31;
    const int slot = bh * NSLOT + CB_OF[qt] + c;
    if (q2 == 0) {
        pm[(size_t)slot * 128 + qloc] = mrow;
        pl[(size_t)slot * 128 + qloc] = lrow;
    }
    _Float16* pob;
    if (c == 0)
        pob = oh + ((size_t)(b * T_ + qt * 128 + qloc)) * D_ + h * 64;
    else
        pob = po + ((size_t)(bh * NPOSLOT + (CB_OF[qt] - qt) + (c - 1)) * 128 + qloc) * 64;
#pragma unroll
    for (int db = 0; db < 2; ++db)
#pragma unroll
        for (int gg = 0; gg < 4; ++gg) {
            halfx4 ov;
#pragma unroll
            for (int j = 0; j < 4; ++j)
                ov[j] = (_Float16)(oacc[db][gg * 4 + j]);
            *(halfx4*)(pob + db * 32 + 8 * gg + 4 * q2) = ov;
        }
}

// ---------------------------------------------------------------------------
// Combine: block per (qt, h, b); thread = (row 0..127, d-half 0..1).
// c=0 partial is read from oh in place; result written back to oh.
// ---------------------------------------------------------------------------
__global__ __launch_bounds__(256) void attn_combine(
    const float* __restrict__ pm, const float* __restrict__ pl,
    const _Float16* __restrict__ po, _Float16* __restrict__ oh)
{
    const int qt = blockIdx.x, h = blockIdx.y, b = blockIdx.z;
    const int nc = NC_OF[qt], cb = CB_OF[qt];
    const int bh = b * H_ + h;
    const int tid = threadIdx.x;
    const int r = tid >> 1, dh = tid & 1;

    const int slot0 = bh * NSLOT + cb;
    float mc[8], lc[8];
    float mstar = -INFINITY;
    for (int cc = 0; cc < nc; ++cc) {
        mc[cc] = pm[(size_t)(slot0 + cc) * 128 + r];
        lc[cc] = pl[(size_t)(slot0 + cc) * 128 + r];
        mstar = fmaxf(mstar, mc[cc]);
    }
    float lstar = 0.f, wc[8];
    for (int cc = 0; cc < nc; ++cc) {
        wc[cc] = exp2f(mc[cc] - mstar);
        lstar += wc[cc] * lc[cc];
    }

    _Float16* ohrow = oh + ((size_t)(b * T_ + qt * 128 + r)) * D_ + h * 64 + dh * 32;

    float acc[32];
    {   // c = 0 from oh
        float wv = wc[0];
#pragma unroll
        for (int g = 0; g < 4; ++g) {
            halfx8 hv = *(const halfx8*)(ohrow + g * 8);
#pragma unroll
            for (int j = 0; j < 8; ++j)
                acc[g * 8 + j] = wv * (float)hv[j];
        }
    }
    const int pbase = bh * NPOSLOT + (cb - qt);
    for (int cc = 1; cc < nc; ++cc) {
        const _Float16* src = po + ((size_t)(pbase + cc - 1) * 128 + r) * 64 + dh * 32;
        float wv = wc[cc];
#pragma unroll
        for (int g = 0; g < 4; ++g) {
            halfx8 hv = *(const halfx8*)(src + g * 8);
#pragma unroll
            for (int j = 0; j < 8; ++j)
                acc[g * 8 + j] += wv * (float)hv[j];
        }
    }
    float linv = 1.f / lstar;
#pragma unroll
    for (int g = 0; g < 4; ++g) {
        halfx8 ov;
#pragma unroll
        for (int j = 0; j < 8; ++j)
            ov[j] = (_Float16)(acc[g * 8 + j] * linv);
        *(halfx8*)(ohrow + g * 8) = ov;
    }
}

// ---------------------------------------------------------------------------
extern "C" void kernel_launch(void* const* d_in, const int* in_sizes, int n_in,
                              void* d_out, int out_size, void* d_ws, size_t ws_size,
                              hipStream_t stream)
{
    (void)in_sizes; (void)n_in; (void)out_size; (void)ws_size;
    const float* x     = (const float*)d_in[0];
    const float* mask  = (const float*)d_in[1];
    const float* w_qkv = (const float*)d_in[2];
    const float* b_qkv = (const float*)d_in[3];
    const float* w_out = (const float*)d_in[4];
    const float* b_out = (const float*)d_in[5];
    float* out = (float*)d_out;

    const size_t QKV1 = (size_t)B_ * H_ * T_ * HD_;   // 4.19M halfs
    _Float16* xh  = (_Float16*)d_ws;
    _Float16* wqh = xh  + (size_t)M_ * K_;
    _Float16* woh = wqh + (size_t)N3_ * K_;
    _Float16* qh  = woh + (size_t)D_ * K_;
    _Float16* kh  = qh  + QKV1;
    _Float16* vth = kh  + QKV1;
    _Float16* oh  = vth + QKV1;
    _Float16* po  = oh  + QKV1;                       // 32*56*128*64 halfs
    float* kbias  = (float*)(po + (size_t)32 * NPOSLOT * 128 * 64);
    float* pm     = kbias + (size_t)B_ * T_;          // 32*72*128 floats
    float* pl     = pm + (size_t)32 * NSLOT * 128;
    int* tflags   = (int*)(pl + (size_t)32 * NSLOT * 128);  // 64 ints

    prep_all<<<4112, 256, 0, stream>>>(x, w_qkv, w_out, mask,
                                       xh, wqh, woh, kbias, tflags);
    gemm_qkv<<<dim3(N3_ / 128, M_ / 128), 256, 0, stream>>>(
        xh, wqh, b_qkv, qh, kh, vth);
    attn_kernel<<<dim3(72, H_, B_), 256, 0, stream>>>(
        qh, kh, vth, kbias, tflags, pm, pl, po, oh);
    attn_combine<<<dim3(16, H_, B_), 256, 0, stream>>>(
        pm, pl, po, oh);
    gemm_out<<<dim3(D_ / 64, M_ / 128), 256, 0, stream>>>(
        oh, woh, b_out, out);
}